// Round 4
// baseline (231.707 us; speedup 1.0000x reference)
//
#include <hip/hip_runtime.h>
#include <hip/hip_bf16.h>
#include <math.h>

// Problem constants
#define BB 512
#define VV 2
#define MM 1024
#define DD 128
#define KMAX 50
#define TOPK 15
#define NBROWS 8192          // 512 b-groups x 16 padded k
#define INV_T (1.0f/0.07f)

// Persistent-kernel geometry: 512 blocks x 256 thr, 2 blocks/CU co-resident
#define NBLK 512
#define NLEAF 16
#define LEAFSZ (NBLK/NLEAF)  // 32

// ---------------- Workspace layout (byte offsets) ----------------
#define OFF_BAR    0         // 4 KB barrier counters (zeroed per call)
#define OFF_ANCH   4096      // bf16 [MM][DD]       256 KB
#define OFF_NVEC   266240    // bf16 [NBROWS][DD]     2 MB
#define OFF_A2     2363392   // f32  [MM]             4 KB
#define OFF_NN2    2367488   // f32  [NBROWS]        32 KB
#define OFF_ACCT   2400256   // f32  [BB][MM]         2 MB   accT[b][i] = acc(i,b)
#define OFF_PART   4497408   // f32  [16][MM]        64 KB   per-jg partial expsums
#define OFF_LSPOS  4562944   // f32  [MM]             4 KB

typedef __attribute__((ext_vector_type(8))) short bf16x8;
typedef __attribute__((ext_vector_type(4))) float f32x4;

// Hierarchical grid barrier: 16 leaf counters (64B apart) -> master -> gen.
// Cross-XCD visibility via __threadfence (agent-scope wb/inv) + agent atomics.
__device__ __forceinline__ void grid_barrier(unsigned* bar)
{
    __syncthreads();
    __threadfence();                       // release this block's stores
    if (threadIdx.x == 0) {
        unsigned* leaf   = bar + (blockIdx.x & (NLEAF - 1)) * 16;
        unsigned* master = bar + NLEAF * 16;
        unsigned* gen    = master + 16;
        unsigned g = __hip_atomic_load(gen, __ATOMIC_RELAXED, __HIP_MEMORY_SCOPE_AGENT);
        bool last = false;
        if (__hip_atomic_fetch_add(leaf, 1u, __ATOMIC_RELAXED, __HIP_MEMORY_SCOPE_AGENT) == LEAFSZ - 1) {
            __hip_atomic_store(leaf, 0u, __ATOMIC_RELAXED, __HIP_MEMORY_SCOPE_AGENT);
            if (__hip_atomic_fetch_add(master, 1u, __ATOMIC_RELAXED, __HIP_MEMORY_SCOPE_AGENT) == NLEAF - 1) {
                __hip_atomic_store(master, 0u, __ATOMIC_RELAXED, __HIP_MEMORY_SCOPE_AGENT);
                __hip_atomic_store(gen, g + 1u, __ATOMIC_RELEASE, __HIP_MEMORY_SCOPE_AGENT);
                last = true;
            }
        }
        if (!last)
            while (__hip_atomic_load(gen, __ATOMIC_RELAXED, __HIP_MEMORY_SCOPE_AGENT) == g)
                __builtin_amdgcn_s_sleep(8);
    }
    __syncthreads();
    __threadfence();                       // acquire: see other XCDs' stores
}

// ---------------------------------------------------------------------------
// One persistent kernel, 4 phases, 3 grid barriers.
// ---------------------------------------------------------------------------
__global__ __launch_bounds__(256, 2) void ccl_mono(
    const float* __restrict__ feat, const int* __restrict__ indices,
    const float* __restrict__ saved, const int* __restrict__ rks,
    float* __restrict__ out, char* __restrict__ ws)
{
    unsigned* bar = (unsigned*)(ws + OFF_BAR);
    __hip_bfloat16* anchor = (__hip_bfloat16*)(ws + OFF_ANCH);
    __hip_bfloat16* nvec   = (__hip_bfloat16*)(ws + OFF_NVEC);
    float* a2    = (float*)(ws + OFF_A2);
    float* nn2   = (float*)(ws + OFF_NN2);
    float* accT  = (float*)(ws + OFF_ACCT);
    float* part  = (float*)(ws + OFF_PART);
    float* lspos = (float*)(ws + OFF_LSPOS);

    __shared__ float pshare[4][16];
    __shared__ float red[4];

    const int tid  = threadIdx.x;
    const int lane = tid & 63;
    const int wid  = tid >> 6;
    const int bid  = blockIdx.x;
    const int lr   = lane & 15;
    const int lg   = lane >> 4;

    // ---------------- P1: gather -> bf16 anchor/nvec + fp32 norms ----------
    {
        const int wv = bid * 4 + wid;            // 0..2047
        for (int row = wv; row < MM + NBROWS; row += NBLK * 4) {
            float2 v;
            __hip_bfloat16* dst;
            if (row < MM) {
                int b = row & (BB - 1), vv = row >> 9;
                v = *(const float2*)&feat[(b * VV + vv) * DD + lane * 2];
                dst = anchor + row * DD;
            } else {
                int j = row - MM;
                int b = j >> 4;
                int k = j & 15; if (k > TOPK - 1) k = TOPK - 1;  // pad dup, masked
                int idx = rks[indices[b] * KMAX + k];
                v = *(const float2*)&saved[(size_t)idx * DD + lane * 2];
                dst = nvec + (size_t)j * DD;
            }
            union { __hip_bfloat16 h[2]; unsigned u; } pk;
            pk.h[0] = __float2bfloat16(v.x);
            pk.h[1] = __float2bfloat16(v.y);
            *(unsigned*)(dst + lane * 2) = pk.u;
            float sq = v.x * v.x + v.y * v.y;
            #pragma unroll
            for (int off = 32; off > 0; off >>= 1) sq += __shfl_xor(sq, off);
            if (lane == 0) {
                if (row < MM) a2[row] = sq;
                else          nn2[row - MM] = sq;
            }
        }
    }
    grid_barrier(bar);

    // ---------------- P2: neighbor MFMA GEMM -> accT[b][i] -----------------
    // 1024 tiles of 64x128 over nvec(8192) x anchor(1024); 2 tiles per block.
    #pragma unroll 1
    for (int t = bid; t < 1024; t += NBLK) {
        const int bx = t & 127;
        const int by = t >> 7;
        const int m0 = bx * 64 + (wid >> 1) * 32;          // nvec row base
        const int j0 = by * 128 + (wid & 1) * 64;          // anchor col base
        f32x4 acc[2][4];
        #pragma unroll
        for (int a = 0; a < 2; ++a)
            #pragma unroll
            for (int b = 0; b < 4; ++b) acc[a][b] = (f32x4){0.f, 0.f, 0.f, 0.f};
        #pragma unroll
        for (int kc = 0; kc < DD; kc += 32) {
            bf16x8 af[2], bf[4];
            #pragma unroll
            for (int tm = 0; tm < 2; ++tm)
                af[tm] = *(const bf16x8*)&nvec[(size_t)(m0 + tm * 16 + lr) * DD + kc + lg * 8];
            #pragma unroll
            for (int tn = 0; tn < 4; ++tn)
                bf[tn] = *(const bf16x8*)&anchor[(size_t)(j0 + tn * 16 + lr) * DD + kc + lg * 8];
            #pragma unroll
            for (int tm = 0; tm < 2; ++tm)
                #pragma unroll
                for (int tn = 0; tn < 4; ++tn)
                    acc[tm][tn] = __builtin_amdgcn_mfma_f32_16x16x32_bf16(
                        af[tm], bf[tn], acc[tm][tn], 0, 0, 0);
        }
        #pragma unroll
        for (int tm = 0; tm < 2; ++tm) {
            const int rowbase = m0 + tm * 16;              // nvec row of C-row 0
            const float4 nn4 = *(const float4*)&nn2[rowbase + lg * 4];
            const float nnr[4] = {nn4.x, nn4.y, nn4.z, nn4.w};
            const int b = rowbase >> 4;
            #pragma unroll
            for (int tn = 0; tn < 4; ++tn) {
                const int j = j0 + tn * 16 + lr;
                const float a2j = a2[j];
                float s = 0.f;
                #pragma unroll
                for (int r = 0; r < 4; ++r) {
                    float g = acc[tm][tn][r];
                    float sq = fmaxf(fmaf(-2.f, g, a2j + nnr[r]), 0.f);
                    float d = __builtin_amdgcn_sqrtf(sq);
                    float f = fmaf(__builtin_amdgcn_rcpf(1.f + d), INV_T, INV_T);
                    if (lg == 3 && r == 3) f = 0.f;        // k==15 pad row
                    s += f;
                }
                s += __shfl_xor(s, 16);
                s += __shfl_xor(s, 32);                    // sum 16 k-rows
                if (lane < 16)
                    accT[(size_t)b * MM + j0 + tn * 16 + lane] = s * (1.0f / TOPK);
            }
        }
    }
    grid_barrier(bar);

    // ---------------- P3: S-tile MFMA + exp partial sums -------------------
    // 1024 tasks (rg 0..63 x jg 0..15): 16 rows x 64 cols each; 2 per block.
    // No max subtraction: ls in [24.7, 49.5] => exp(ls) <= 3e21 fits fp32.
    #pragma unroll 1
    for (int t = bid; t < 1024; t += NBLK) {
        const int rg = t >> 4, jg = t & 15;
        const int i0 = rg * 16;
        const int j0 = jg * 64;
        const int jcol = j0 + wid * 16 + lr;               // this lane's j
        f32x4 acc = (f32x4){0.f, 0.f, 0.f, 0.f};
        #pragma unroll
        for (int kc = 0; kc < DD; kc += 32) {
            bf16x8 af = *(const bf16x8*)&anchor[(size_t)(i0 + lr) * DD + kc + lg * 8];
            bf16x8 bf = *(const bf16x8*)&anchor[(size_t)jcol * DD + kc + lg * 8];
            acc = __builtin_amdgcn_mfma_f32_16x16x32_bf16(af, bf, acc, 0, 0, 0);
        }
        const int ib4 = i0 + lg * 4;                       // 4 rows of this lane
        const float4 a2i4 = *(const float4*)&a2[ib4];
        const float a2iv[4] = {a2i4.x, a2i4.y, a2i4.z, a2i4.w};
        const float a2j = a2[jcol];
        const float4 aij4 = *(const float4*)&accT[(size_t)(jcol & (BB - 1)) * MM + ib4];
        const float aijv[4] = {aij4.x, aij4.y, aij4.z, aij4.w};
        float esum[4];
        #pragma unroll
        for (int r = 0; r < 4; ++r) {
            const int i = ib4 + r;
            float g = acc[r];
            float sq = fmaxf(fmaf(-2.f, g, a2iv[r] + a2j), 0.f);
            float d0 = __builtin_amdgcn_sqrtf(sq);
            float adc = fmaf(__builtin_amdgcn_rcpf(1.f + d0), INV_T, INV_T);
            float aji = accT[(size_t)(i & (BB - 1)) * MM + jcol];
            float ls = __builtin_amdgcn_sqrtf(aijv[r] * aijv[r] + aji * aji + adc * adc);
            esum[r] = (jcol == i) ? 0.f : __expf(ls);
            if (jcol == (i ^ BB)) lspos[i] = ls;           // the positive pair
        }
        #pragma unroll
        for (int r = 0; r < 4; ++r) {
            float e = esum[r];
            e += __shfl_xor(e, 1);
            e += __shfl_xor(e, 2);
            e += __shfl_xor(e, 4);
            e += __shfl_xor(e, 8);                         // sum 16 j's in wave
            if (lr == 0) pshare[wid][lg * 4 + r] = e;
        }
        __syncthreads();
        if (tid < 16)
            part[jg * MM + i0 + tid] =
                pshare[0][tid] + pshare[1][tid] + pshare[2][tid] + pshare[3][tid];
        __syncthreads();
    }
    grid_barrier(bar);

    // ---------------- P4: loss per row + mean (block 0 only) ---------------
    if (bid == 0) {
        float lsum = 0.f;
        #pragma unroll
        for (int q = 0; q < 4; ++q) {
            const int i = tid + q * 256;
            float s = 0.f;
            #pragma unroll
            for (int jg = 0; jg < 16; ++jg) s += part[jg * MM + i];
            lsum += __logf(s) - lspos[i];
        }
        #pragma unroll
        for (int off = 32; off > 0; off >>= 1) lsum += __shfl_xor(lsum, off);
        if (lane == 0) red[wid] = lsum;
        __syncthreads();
        if (tid == 0)
            out[0] = (red[0] + red[1] + red[2] + red[3]) * (1.0f / MM);
    }
}

// ---------------------------------------------------------------------------
extern "C" void kernel_launch(void* const* d_in, const int* in_sizes, int n_in,
                              void* d_out, int out_size, void* d_ws, size_t ws_size,
                              hipStream_t stream)
{
    const float* feat    = (const float*)d_in[0];  // (512, 2, 128) f32
    const int*   indices = (const int*)  d_in[1];  // (512,) i32
    const float* saved   = (const float*)d_in[2];  // (100000, 128) f32
    const int*   rks     = (const int*)  d_in[3];  // (100000, 50) i32

    // zero the barrier counters every call (ws is poisoned once to 0xAA)
    hipMemsetAsync((char*)d_ws + OFF_BAR, 0, 4096, stream);
    ccl_mono<<<NBLK, 256, 0, stream>>>(feat, indices, saved, rks,
                                       (float*)d_out, (char*)d_ws);
}

// Round 5
// 43.406 us; speedup vs baseline: 5.3381x; 5.3381x over previous
//
#include <hip/hip_runtime.h>
#include <math.h>

// Problem constants
#define BB 512
#define VV 2
#define MM 1024
#define DD 128
#define KMAX 50
#define TOPK 15
#define INV_T (1.0f/0.07f)

// ---------------- Workspace layout (byte offsets) ----------------
#define OFF_ACCT  0                     // f32 [BB][MM]  2 MB : accT[b][i] = acc(i,b)
#define OFF_PART  (2*1024*1024)         // f32 [16][MM] 64 KB : per-jg partial expsums
#define OFF_LSPOS (OFF_PART + 65536)    // f32 [MM]      4 KB : logit of the positive pair

typedef __attribute__((ext_vector_type(8))) short bf16x8;
typedef __attribute__((ext_vector_type(4))) float f32x4;

// f32 -> bf16 (RNE), 3 VALU ops, no header dependency
__device__ __forceinline__ short f2bf(float x)
{
    union { float f; unsigned u; } a; a.f = x;
    return (short)((a.u + 0x7FFFu + ((a.u >> 16) & 1u)) >> 16);
}

// convert 8 f32 (two float4) to bf16x8, accumulating sum of squares
__device__ __forceinline__ bf16x8 cvt8(float4 p0, float4 p1, float& nacc)
{
    float v[8] = {p0.x, p0.y, p0.z, p0.w, p1.x, p1.y, p1.z, p1.w};
    bf16x8 r;
    #pragma unroll
    for (int e = 0; e < 8; ++e) {
        nacc = fmaf(v[e], v[e], nacc);
        r[e] = f2bf(v[e]);
    }
    return r;
}

// anchor row i lives at feat[((i&511)*2 + (i>>9)) * 128 + d]
__device__ __forceinline__ const float4* anchor_ptr(const float* feat, int i, int d)
{
    int frow = (i & (BB - 1)) * VV + (i >> 9);
    return (const float4*)&feat[(size_t)frow * DD + d];
}

// ---------------------------------------------------------------------------
// K1: fused neighbor MFMA GEMM -> accT[b][i].
// Reads saved/rks/indices + feat directly (f32 -> bf16 in-register), exact f32
// norms computed in-block. Grid (128, 8), 256 thr = 4 waves (2x2).
// Block tile: 64 neighbor rows x 128 anchor cols; wave tile 32 x 64.
// C layout (mfma_f32_16x16x32_bf16): col = lane&15, row = (lane>>4)*4 + reg.
// ---------------------------------------------------------------------------
__global__ __launch_bounds__(256) void k1_acc(
    const float* __restrict__ feat, const int* __restrict__ indices,
    const float* __restrict__ saved, const int* __restrict__ rks,
    float* __restrict__ accT)
{
    const int tid = threadIdx.x;
    const int lane = tid & 63;
    const int wid = tid >> 6;
    const int lr = lane & 15;
    const int lg = lane >> 4;
    const int m0 = blockIdx.x * 64 + (wid >> 1) * 32;   // neighbor row base
    const int j0 = blockIdx.y * 128 + (wid & 1) * 64;   // anchor col base

    // neighbor row = b*16 + k, k = lr (k=15 exists in rks, masked in epilogue)
    int aidx[2];
    #pragma unroll
    for (int tm = 0; tm < 2; ++tm) {
        int b = (m0 >> 4) + tm * 1;                     // (m0 + tm*16) >> 4
        aidx[tm] = rks[(size_t)indices[b] * KMAX + lr];
    }

    f32x4 acc[2][4];
    #pragma unroll
    for (int a = 0; a < 2; ++a)
        #pragma unroll
        for (int b = 0; b < 4; ++b) acc[a][b] = (f32x4){0.f, 0.f, 0.f, 0.f};
    float nnA[2] = {0.f, 0.f};
    float nnB[4] = {0.f, 0.f, 0.f, 0.f};

    #pragma unroll
    for (int kc = 0; kc < DD; kc += 32) {
        bf16x8 af[2], bf[4];
        #pragma unroll
        for (int tm = 0; tm < 2; ++tm) {
            const float4* p = (const float4*)&saved[(size_t)aidx[tm] * DD + kc + lg * 8];
            af[tm] = cvt8(p[0], p[1], nnA[tm]);
        }
        #pragma unroll
        for (int tn = 0; tn < 4; ++tn) {
            const float4* p = anchor_ptr(feat, j0 + tn * 16 + lr, kc + lg * 8);
            bf[tn] = cvt8(p[0], p[1], nnB[tn]);
        }
        #pragma unroll
        for (int tm = 0; tm < 2; ++tm)
            #pragma unroll
            for (int tn = 0; tn < 4; ++tn)
                acc[tm][tn] = __builtin_amdgcn_mfma_f32_16x16x32_bf16(
                    af[tm], bf[tn], acc[tm][tn], 0, 0, 0);
    }

    // complete norms: sum the 4 lg-group partials (each lane then holds the
    // full norm of the row with index == its lr within the 16-row sub-tile)
    #pragma unroll
    for (int tm = 0; tm < 2; ++tm) {
        nnA[tm] += __shfl_xor(nnA[tm], 16);
        nnA[tm] += __shfl_xor(nnA[tm], 32);
    }
    #pragma unroll
    for (int tn = 0; tn < 4; ++tn) {
        nnB[tn] += __shfl_xor(nnB[tn], 16);
        nnB[tn] += __shfl_xor(nnB[tn], 32);
    }
    // norm of C-row (k = lg*4 + r) for this lane
    float nnAr[2][4];
    #pragma unroll
    for (int tm = 0; tm < 2; ++tm)
        #pragma unroll
        for (int r = 0; r < 4; ++r)
            nnAr[tm][r] = __shfl(nnA[tm], lg * 4 + r);

    #pragma unroll
    for (int tm = 0; tm < 2; ++tm) {
        const int b = (m0 >> 4) + tm;
        #pragma unroll
        for (int tn = 0; tn < 4; ++tn) {
            const float a2j = nnB[tn];                  // lane's own col norm
            float s = 0.f;
            #pragma unroll
            for (int r = 0; r < 4; ++r) {
                float g = acc[tm][tn][r];
                float sq = fmaxf(fmaf(-2.f, g, a2j + nnAr[tm][r]), 0.f);
                float d = __builtin_amdgcn_sqrtf(sq);
                float f = fmaf(__builtin_amdgcn_rcpf(1.f + d), INV_T, INV_T);
                if (lg == 3 && r == 3) f = 0.f;         // k == 15 pad row
                s += f;
            }
            s += __shfl_xor(s, 16);
            s += __shfl_xor(s, 32);                     // sum the 16 k-rows
            if (lane < 16)
                accT[(size_t)b * MM + j0 + tn * 16 + lane] = s * (1.0f / TOPK);
        }
    }
}

// ---------------------------------------------------------------------------
// K2: S-tile MFMA + adc + ls + exp partial sums (no max subtraction:
// ls in [24.7, 49.5] => exp fits fp32 comfortably; verified round 4).
// Grid (64, 16): 16 i-rows x 64 j-cols per block; wave handles 16 cols.
// ---------------------------------------------------------------------------
__global__ __launch_bounds__(256) void k2_exp(
    const float* __restrict__ feat, const float* __restrict__ accT,
    float* __restrict__ part, float* __restrict__ lspos)
{
    __shared__ float pshare[4][16];
    const int tid = threadIdx.x;
    const int lane = tid & 63;
    const int wid = tid >> 6;
    const int lr = lane & 15;
    const int lg = lane >> 4;
    const int i0 = blockIdx.x * 16;
    const int jg = blockIdx.y;
    const int jcol = jg * 64 + wid * 16 + lr;

    f32x4 acc = (f32x4){0.f, 0.f, 0.f, 0.f};
    float pA = 0.f, pB = 0.f;
    #pragma unroll
    for (int kc = 0; kc < DD; kc += 32) {
        const float4* pa = anchor_ptr(feat, i0 + lr, kc + lg * 8);
        bf16x8 af = cvt8(pa[0], pa[1], pA);
        const float4* pb = anchor_ptr(feat, jcol, kc + lg * 8);
        bf16x8 bf = cvt8(pb[0], pb[1], pB);
        acc = __builtin_amdgcn_mfma_f32_16x16x32_bf16(af, bf, acc, 0, 0, 0);
    }
    pA += __shfl_xor(pA, 16); pA += __shfl_xor(pA, 32);
    pB += __shfl_xor(pB, 16); pB += __shfl_xor(pB, 32);

    const int ib4 = i0 + lg * 4;
    float a2iv[4];
    #pragma unroll
    for (int r = 0; r < 4; ++r) a2iv[r] = __shfl(pA, lg * 4 + r);
    const float a2j = pB;                               // lane's own col norm
    const float4 aij4 = *(const float4*)&accT[(size_t)(jcol & (BB - 1)) * MM + ib4];
    const float aijv[4] = {aij4.x, aij4.y, aij4.z, aij4.w};

    float esum[4];
    #pragma unroll
    for (int r = 0; r < 4; ++r) {
        const int i = ib4 + r;
        float g = acc[r];
        float sq = fmaxf(fmaf(-2.f, g, a2iv[r] + a2j), 0.f);
        float d0 = __builtin_amdgcn_sqrtf(sq);
        float adc = fmaf(__builtin_amdgcn_rcpf(1.f + d0), INV_T, INV_T);
        float aji = accT[(size_t)(i & (BB - 1)) * MM + jcol];
        float ls = __builtin_amdgcn_sqrtf(aijv[r] * aijv[r] + aji * aji + adc * adc);
        esum[r] = (jcol == i) ? 0.f : __expf(ls);
        if (jcol == (i ^ BB)) lspos[i] = ls;            // the positive pair
    }
    #pragma unroll
    for (int r = 0; r < 4; ++r) {
        float e = esum[r];
        e += __shfl_xor(e, 1);
        e += __shfl_xor(e, 2);
        e += __shfl_xor(e, 4);
        e += __shfl_xor(e, 8);                          // sum 16 j's in wave
        if (lr == 0) pshare[wid][lg * 4 + r] = e;
    }
    __syncthreads();
    if (tid < 16)
        part[jg * MM + i0 + tid] =
            pshare[0][tid] + pshare[1][tid] + pshare[2][tid] + pshare[3][tid];
}

// ---------------------------------------------------------------------------
// K3: finish — loss per row + mean, single block.
// ---------------------------------------------------------------------------
__global__ __launch_bounds__(256) void k3_finish(
    const float* __restrict__ part, const float* __restrict__ lspos,
    float* __restrict__ out)
{
    __shared__ float red[4];
    const int tid = threadIdx.x;
    const int lane = tid & 63, w = tid >> 6;
    float lsum = 0.f;
    #pragma unroll
    for (int q = 0; q < 4; ++q) {
        const int i = tid + q * 256;
        float s = 0.f;
        #pragma unroll
        for (int jg = 0; jg < 16; ++jg) s += part[jg * MM + i];
        lsum += __logf(s) - lspos[i];
    }
    #pragma unroll
    for (int off = 32; off > 0; off >>= 1) lsum += __shfl_xor(lsum, off);
    if (lane == 0) red[w] = lsum;
    __syncthreads();
    if (tid == 0) out[0] = (red[0] + red[1] + red[2] + red[3]) * (1.0f / MM);
}

// ---------------------------------------------------------------------------
extern "C" void kernel_launch(void* const* d_in, const int* in_sizes, int n_in,
                              void* d_out, int out_size, void* d_ws, size_t ws_size,
                              hipStream_t stream)
{
    const float* feat    = (const float*)d_in[0];  // (512, 2, 128) f32
    const int*   indices = (const int*)  d_in[1];  // (512,) i32
    const float* saved   = (const float*)d_in[2];  // (100000, 128) f32
    const int*   rks     = (const int*)  d_in[3];  // (100000, 50) i32

    char* w = (char*)d_ws;
    float* accT  = (float*)(w + OFF_ACCT);
    float* part  = (float*)(w + OFF_PART);
    float* lspos = (float*)(w + OFF_LSPOS);

    // K1: fused neighbor GEMM -> accT (reads inputs directly, no staging)
    k1_acc<<<dim3(128, 8), 256, 0, stream>>>(feat, indices, saved, rks, accT);
    // K2: S-GEMM + adc + exp partials -> part, lspos
    k2_exp<<<dim3(64, 16), 256, 0, stream>>>(feat, accT, part, lspos);
    // K3: loss + mean
    k3_finish<<<1, 256, 0, stream>>>(part, lspos, (float*)d_out);
}

// Round 6
// 35.703 us; speedup vs baseline: 6.4899x; 1.2158x over previous
//
#include <hip/hip_runtime.h>
#include <math.h>

// Problem constants
#define BB 512
#define VV 2
#define MM 1024
#define DD 128
#define KMAX 50
#define TOPK 15
#define INV_T (1.0f/0.07f)

// ---------------- Workspace layout (byte offsets) ----------------
#define OFF_ANCH  0                      // bf16 [MM][DD]   256 KB
#define OFF_A2    262144                 // f32  [MM]         4 KB
#define OFF_ACCT  266240                 // f32  [BB][MM]     2 MB : accT[b][i] = acc(i,b)
#define OFF_PART  (266240 + 2097152)     // f32  [16][MM]    64 KB : per-jg partial expsums
#define OFF_LSPOS (OFF_PART + 65536)     // f32  [MM]         4 KB

typedef __attribute__((ext_vector_type(8))) short bf16x8;
typedef __attribute__((ext_vector_type(4))) float f32x4;

// f32 -> bf16 (RNE)
__device__ __forceinline__ short f2bf(float x)
{
    union { float f; unsigned u; } a; a.f = x;
    return (short)((a.u + 0x7FFFu + ((a.u >> 16) & 1u)) >> 16);
}

// convert 8 f32 (two float4) to bf16x8, accumulating sum of squares
__device__ __forceinline__ bf16x8 cvt8(float4 p0, float4 p1, float& nacc)
{
    float v[8] = {p0.x, p0.y, p0.z, p0.w, p1.x, p1.y, p1.z, p1.w};
    bf16x8 r;
    #pragma unroll
    for (int e = 0; e < 8; ++e) {
        nacc = fmaf(v[e], v[e], nacc);
        r[e] = f2bf(v[e]);
    }
    return r;
}

// ---------------------------------------------------------------------------
// K0: anchor (transposed features) -> bf16 + exact f32 norms.
// 256 blocks x 256 thr; wave per row.
// ---------------------------------------------------------------------------
__global__ __launch_bounds__(256) void k0_anchor(
    const float* __restrict__ feat,
    unsigned* __restrict__ anchor_u,     // bf16 pairs packed as u32
    float* __restrict__ a2)
{
    const int row  = blockIdx.x * 4 + (threadIdx.x >> 6);
    const int lane = threadIdx.x & 63;
    const int frow = (row & (BB - 1)) * VV + (row >> 9);
    float2 v = *(const float2*)&feat[(size_t)frow * DD + lane * 2];
    unsigned lo = (unsigned)(unsigned short)f2bf(v.x);
    unsigned hi = (unsigned)(unsigned short)f2bf(v.y);
    anchor_u[row * (DD / 2) + lane] = lo | (hi << 16);
    float sq = v.x * v.x + v.y * v.y;
    #pragma unroll
    for (int off = 32; off > 0; off >>= 1) sq += __shfl_xor(sq, off);
    if (lane == 0) a2[row] = sq;
}

// ---------------------------------------------------------------------------
// K1: neighbor MFMA GEMM -> accT[b][i].
// Grid (128, 4): block owns 4 b-groups (64 neighbor rows) x 256 anchor cols.
// A-fragments (gathered from saved, cvt to bf16) + norms loaded ONCE,
// reused over inner j-loop (2 iterations x 128 cols). Waves 2x2.
// C layout (mfma_f32_16x16x32_bf16): col = lane&15, row = (lane>>4)*4 + reg.
// ---------------------------------------------------------------------------
__global__ __launch_bounds__(256) void k1_acc(
    const short* __restrict__ anchor,    // bf16 [MM][DD]
    const float* __restrict__ a2,
    const int* __restrict__ indices,
    const float* __restrict__ saved, const int* __restrict__ rks,
    float* __restrict__ accT)
{
    const int tid = threadIdx.x;
    const int lane = tid & 63;
    const int wid = tid >> 6;
    const int lr = lane & 15;
    const int lg = lane >> 4;
    const int wr = wid >> 1;
    const int wc = wid & 1;
    const int m0 = blockIdx.x * 64 + wr * 32;           // neighbor row base

    // gather A fragments once: rows m0 + tm*16 + lr, k-chunks lg*8 within kc*32
    int aidx[2];
    #pragma unroll
    for (int tm = 0; tm < 2; ++tm) {
        int b = (m0 >> 4) + tm;
        aidx[tm] = rks[(size_t)indices[b] * KMAX + lr];  // k = lr (15 masked later)
    }
    bf16x8 af[2][4];
    float nnA[2] = {0.f, 0.f};
    #pragma unroll
    for (int tm = 0; tm < 2; ++tm)
        #pragma unroll
        for (int kc = 0; kc < 4; ++kc) {
            const float4* p = (const float4*)&saved[(size_t)aidx[tm] * DD + kc * 32 + lg * 8];
            af[tm][kc] = cvt8(p[0], p[1], nnA[tm]);
        }
    #pragma unroll
    for (int tm = 0; tm < 2; ++tm) {
        nnA[tm] += __shfl_xor(nnA[tm], 16);
        nnA[tm] += __shfl_xor(nnA[tm], 32);             // lane holds norm of row lr
    }
    float nnAr[2][4];
    #pragma unroll
    for (int tm = 0; tm < 2; ++tm)
        #pragma unroll
        for (int r = 0; r < 4; ++r)
            nnAr[tm][r] = __shfl(nnA[tm], lg * 4 + r);  // norm of C-row lg*4+r

    #pragma unroll
    for (int jt = 0; jt < 2; ++jt) {
        const int j0 = blockIdx.y * 256 + jt * 128 + wc * 64;
        f32x4 acc[2][4];
        #pragma unroll
        for (int a = 0; a < 2; ++a)
            #pragma unroll
            for (int b = 0; b < 4; ++b) acc[a][b] = (f32x4){0.f, 0.f, 0.f, 0.f};
        #pragma unroll
        for (int kc = 0; kc < 4; ++kc) {
            bf16x8 bf[4];
            #pragma unroll
            for (int tn = 0; tn < 4; ++tn)
                bf[tn] = *(const bf16x8*)&anchor[(size_t)(j0 + tn * 16 + lr) * DD + kc * 32 + lg * 8];
            #pragma unroll
            for (int tm = 0; tm < 2; ++tm)
                #pragma unroll
                for (int tn = 0; tn < 4; ++tn)
                    acc[tm][tn] = __builtin_amdgcn_mfma_f32_16x16x32_bf16(
                        af[tm][kc], bf[tn], acc[tm][tn], 0, 0, 0);
        }
        #pragma unroll
        for (int tm = 0; tm < 2; ++tm) {
            const int b = (m0 >> 4) + tm;
            #pragma unroll
            for (int tn = 0; tn < 4; ++tn) {
                const float a2j = a2[j0 + tn * 16 + lr];
                float s = 0.f;
                #pragma unroll
                for (int r = 0; r < 4; ++r) {
                    float g = acc[tm][tn][r];
                    float sq = fmaxf(fmaf(-2.f, g, a2j + nnAr[tm][r]), 0.f);
                    float d = __builtin_amdgcn_sqrtf(sq);
                    float f = fmaf(__builtin_amdgcn_rcpf(1.f + d), INV_T, INV_T);
                    if (lg == 3 && r == 3) f = 0.f;     // k == 15 pad row
                    s += f;
                }
                s += __shfl_xor(s, 16);
                s += __shfl_xor(s, 32);                 // sum the 16 k-rows
                if (lane < 16)
                    accT[(size_t)b * MM + j0 + tn * 16 + lane] = s * (1.0f / TOPK);
            }
        }
    }
}

// ---------------------------------------------------------------------------
// K2: S-tile MFMA + adc + ls + exp partial sums (no max subtraction:
// ls in [24.7, 49.5] => exp fits fp32; verified rounds 4-5, absmax 0).
// Grid (64, 16): 16 i-rows x 64 j-cols per block; wave handles 16 cols.
// ---------------------------------------------------------------------------
__global__ __launch_bounds__(256) void k2_exp(
    const short* __restrict__ anchor, const float* __restrict__ a2,
    const float* __restrict__ accT,
    float* __restrict__ part, float* __restrict__ lspos)
{
    __shared__ float pshare[4][16];
    const int tid = threadIdx.x;
    const int lane = tid & 63;
    const int wid = tid >> 6;
    const int lr = lane & 15;
    const int lg = lane >> 4;
    const int i0 = blockIdx.x * 16;
    const int jg = blockIdx.y;
    const int jcol = jg * 64 + wid * 16 + lr;

    f32x4 acc = (f32x4){0.f, 0.f, 0.f, 0.f};
    #pragma unroll
    for (int kc = 0; kc < 4; ++kc) {
        bf16x8 af = *(const bf16x8*)&anchor[(size_t)(i0 + lr) * DD + kc * 32 + lg * 8];
        bf16x8 bf = *(const bf16x8*)&anchor[(size_t)jcol * DD + kc * 32 + lg * 8];
        acc = __builtin_amdgcn_mfma_f32_16x16x32_bf16(af, bf, acc, 0, 0, 0);
    }
    const int ib4 = i0 + lg * 4;
    const float4 a2i4 = *(const float4*)&a2[ib4];
    const float a2iv[4] = {a2i4.x, a2i4.y, a2i4.z, a2i4.w};
    const float a2j = a2[jcol];
    const float4 aij4 = *(const float4*)&accT[(size_t)(jcol & (BB - 1)) * MM + ib4];
    const float aijv[4] = {aij4.x, aij4.y, aij4.z, aij4.w};

    float esum[4];
    #pragma unroll
    for (int r = 0; r < 4; ++r) {
        const int i = ib4 + r;
        float g = acc[r];
        float sq = fmaxf(fmaf(-2.f, g, a2iv[r] + a2j), 0.f);
        float d0 = __builtin_amdgcn_sqrtf(sq);
        float adc = fmaf(__builtin_amdgcn_rcpf(1.f + d0), INV_T, INV_T);
        float aji = accT[(size_t)(i & (BB - 1)) * MM + jcol];
        float ls = __builtin_amdgcn_sqrtf(aijv[r] * aijv[r] + aji * aji + adc * adc);
        esum[r] = (jcol == i) ? 0.f : __expf(ls);
        if (jcol == (i ^ BB)) lspos[i] = ls;            // the positive pair
    }
    #pragma unroll
    for (int r = 0; r < 4; ++r) {
        float e = esum[r];
        e += __shfl_xor(e, 1);
        e += __shfl_xor(e, 2);
        e += __shfl_xor(e, 4);
        e += __shfl_xor(e, 8);                          // sum 16 j's in wave
        if (lr == 0) pshare[wid][lg * 4 + r] = e;
    }
    __syncthreads();
    if (tid < 16)
        part[jg * MM + i0 + tid] =
            pshare[0][tid] + pshare[1][tid] + pshare[2][tid] + pshare[3][tid];
}

// ---------------------------------------------------------------------------
// K3: finish — loss per row + mean, single block.
// ---------------------------------------------------------------------------
__global__ __launch_bounds__(256) void k3_finish(
    const float* __restrict__ part, const float* __restrict__ lspos,
    float* __restrict__ out)
{
    __shared__ float red[4];
    const int tid = threadIdx.x;
    const int lane = tid & 63, w = tid >> 6;
    float lsum = 0.f;
    #pragma unroll
    for (int q = 0; q < 4; ++q) {
        const int i = tid + q * 256;
        float s = 0.f;
        #pragma unroll
        for (int jg = 0; jg < 16; ++jg) s += part[jg * MM + i];
        lsum += __logf(s) - lspos[i];
    }
    #pragma unroll
    for (int off = 32; off > 0; off >>= 1) lsum += __shfl_xor(lsum, off);
    if (lane == 0) red[w] = lsum;
    __syncthreads();
    if (tid == 0) out[0] = (red[0] + red[1] + red[2] + red[3]) * (1.0f / MM);
}

// ---------------------------------------------------------------------------
extern "C" void kernel_launch(void* const* d_in, const int* in_sizes, int n_in,
                              void* d_out, int out_size, void* d_ws, size_t ws_size,
                              hipStream_t stream)
{
    const float* feat    = (const float*)d_in[0];  // (512, 2, 128) f32
    const int*   indices = (const int*)  d_in[1];  // (512,) i32
    const float* saved   = (const float*)d_in[2];  // (100000, 128) f32
    const int*   rks     = (const int*)  d_in[3];  // (100000, 50) i32

    char* w = (char*)d_ws;
    short* anchor = (short*)(w + OFF_ANCH);
    float* a2     = (float*)(w + OFF_A2);
    float* accT   = (float*)(w + OFF_ACCT);
    float* part   = (float*)(w + OFF_PART);
    float* lspos  = (float*)(w + OFF_LSPOS);

    // K0: anchor -> bf16 + exact norms
    k0_anchor<<<MM / 4, 256, 0, stream>>>(feat, (unsigned*)anchor, a2);
    // K1: neighbor GEMM -> accT (gathers saved rows once per 4 j-blocks)
    k1_acc<<<dim3(128, 4), 256, 0, stream>>>(anchor, a2, indices, saved, rks, accT);
    // K2: S-GEMM + adc + exp partials -> part, lspos
    k2_exp<<<dim3(64, 16), 256, 0, stream>>>(anchor, a2, accT, part, lspos);
    // K3: loss + mean
    k3_finish<<<1, 256, 0, stream>>>(part, lspos, (float*)d_out);
}